// Round 1
// baseline (315.451 us; speedup 1.0000x reference)
//
#include <hip/hip_runtime.h>

#define BB 32
#define LL 32768
#define HH 32
#define NN2 8
#define NCOND 4
#define NCHUNK 128
#define LC (LL / NCHUNK)   // 256

// ws layout (floats):
//  PARAM_OFF: (wr, wi, ctr, cti) per (h,n)        H*N2*4   = 1024
//  WLC_OFF  : (wLc_r, wLc_i) per (h,n)            H*N2*2   = 512   (at 1024)
//  FILM_OFF : (gamma, beta) per (b,h)             B*H*2    = 2048  (at 1536)
//  S_OFF    : chunk-local end states              B*H*NCHUNK*N2*2  (at 4096)
//  ZIN_OFF  : chunk initial states                same size
#define PARAM_OFF 0
#define WLC_OFF   1024
#define FILM_OFF  1536
#define S_OFF     4096
#define SZ_S      (BB * HH * NCHUNK * NN2 * 2)   // 2,097,152 floats
#define ZIN_OFF   (S_OFF + SZ_S)                 // total ~16.8 MB

__global__ void setup_kernel(const float* __restrict__ log_dt,
                             const float* __restrict__ C_re,
                             const float* __restrict__ C_im,
                             const float* __restrict__ log_A_real,
                             const float* __restrict__ A_imag,
                             const float* __restrict__ cond,
                             const float* __restrict__ film_W,
                             const float* __restrict__ film_b,
                             float* __restrict__ ws) {
  int idx = blockIdx.x * blockDim.x + threadIdx.x;
  if (idx < HH * NN2) {
    int h = idx >> 3;
    float dt = expf(log_dt[h]);
    float ar = -expf(log_A_real[idx]);
    float ai = A_imag[idx];
    float dr = ar * dt, di = ai * dt;        // dtA
    float er = expf(dr);
    float wr = er * cosf(di);
    float wi = er * sinf(di);
    // (exp(dtA)-1)/A
    float den = ar * ar + ai * ai;
    float tr = ((wr - 1.f) * ar + wi * ai) / den;
    float ti = (wi * ar - (wr - 1.f) * ai) / den;
    float cr = C_re[idx], ci = C_im[idx];
    float ctr = 2.f * (cr * tr - ci * ti);
    float cti = 2.f * (cr * ti + ci * tr);
    float* p = ws + PARAM_OFF + idx * 4;
    p[0] = wr; p[1] = wi; p[2] = ctr; p[3] = cti;
    // w^LC
    float eL  = expf(dr * (float)LC);
    float wlr = eL * cosf(di * (float)LC);
    float wli = eL * sinf(di * (float)LC);
    float* q = ws + WLC_OFF + idx * 2;
    q[0] = wlr; q[1] = wli;
  }
  int f = idx - HH * NN2;
  if (f >= 0 && f < BB * HH) {
    int b = f >> 5, h = f & (HH - 1);
    float g  = film_b[h];
    float be = film_b[h + HH];
    #pragma unroll
    for (int c2 = 0; c2 < NCOND; c2++) {
      float cv = cond[b * NCOND + c2];
      g  = fmaf(cv, film_W[c2 * 2 * HH + h], g);
      be = fmaf(cv, film_W[c2 * 2 * HH + HH + h], be);
    }
    float* p = ws + FILM_OFF + f * 2;
    p[0] = g; p[1] = be;
  }
}

__global__ __launch_bounds__(256) void pass_a(const float* __restrict__ x,
                                              float* __restrict__ ws) {
  const int flat = blockIdx.x * 256 + threadIdx.x;
  const int h = flat & (HH - 1);
  const int c = (flat >> 5) & (NCHUNK - 1);
  const int b = flat >> 12;
  const float4* pp = (const float4*)(ws + PARAM_OFF);
  float wr[NN2], wi[NN2], zr[NN2], zi[NN2];
  #pragma unroll
  for (int n = 0; n < NN2; n++) {
    float4 p = pp[h * NN2 + n];
    wr[n] = p.x; wi[n] = p.y;
    zr[n] = 0.f; zi[n] = 0.f;
  }
  const float* xp = x + ((size_t)b * LL + (size_t)c * LC) * HH + h;
  for (int i = 0; i < LC; i += 8) {
    float u[8];
    #pragma unroll
    for (int j = 0; j < 8; j++) u[j] = xp[(size_t)(i + j) * HH];
    #pragma unroll
    for (int j = 0; j < 8; j++) {
      #pragma unroll
      for (int n = 0; n < NN2; n++) {
        float t0  = fmaf(-wi[n], zi[n], u[j]);
        float nzr = fmaf(wr[n], zr[n], t0);
        float nzi = fmaf(wr[n], zi[n], wi[n] * zr[n]);
        zr[n] = nzr; zi[n] = nzi;
      }
    }
  }
  float4* Sp = (float4*)(ws + S_OFF) + (size_t)flat * 4;
  #pragma unroll
  for (int q = 0; q < 4; q++)
    Sp[q] = make_float4(zr[q * 2], zi[q * 2], zr[q * 2 + 1], zi[q * 2 + 1]);
}

__global__ void pass_b(float* __restrict__ ws) {
  int idx = blockIdx.x * blockDim.x + threadIdx.x;  // B*H*N2 = 8192
  int n = idx & (NN2 - 1);
  int h = (idx >> 3) & (HH - 1);
  int b = idx >> 8;
  float wlr = ws[WLC_OFF + (h * NN2 + n) * 2];
  float wli = ws[WLC_OFF + (h * NN2 + n) * 2 + 1];
  float Zr = 0.f, Zi = 0.f;
  const size_t stride = (size_t)HH * NN2 * 2;   // per-chunk stride
  size_t base = ((size_t)b * NCHUNK * HH + h) * (NN2 * 2) + n * 2;
  for (int c = 0; c < NCHUNK; c++) {
    size_t e = base + (size_t)c * stride;
    ws[ZIN_OFF + e]     = Zr;
    ws[ZIN_OFF + e + 1] = Zi;
    float sr = ws[S_OFF + e];
    float si = ws[S_OFF + e + 1];
    float nZr = fmaf(wlr, Zr, fmaf(-wli, Zi, sr));
    float nZi = fmaf(wlr, Zi, fmaf(wli, Zr, si));
    Zr = nZr; Zi = nZi;
  }
}

__global__ __launch_bounds__(256) void pass_c(const float* __restrict__ x,
                                              const float* __restrict__ Dv,
                                              float* __restrict__ out,
                                              float* __restrict__ ws) {
  const int flat = blockIdx.x * 256 + threadIdx.x;
  const int h = flat & (HH - 1);
  const int c = (flat >> 5) & (NCHUNK - 1);
  const int b = flat >> 12;
  float wr[NN2], wi[NN2], ctr[NN2], cti[NN2], zr[NN2], zi[NN2];
  const float4* pp = (const float4*)(ws + PARAM_OFF);
  #pragma unroll
  for (int n = 0; n < NN2; n++) {
    float4 p = pp[h * NN2 + n];
    wr[n] = p.x; wi[n] = p.y; ctr[n] = p.z; cti[n] = p.w;
  }
  const float4* Zp = (const float4*)(ws + ZIN_OFF) + (size_t)flat * 4;
  #pragma unroll
  for (int q = 0; q < 4; q++) {
    float4 z = Zp[q];
    zr[q * 2] = z.x; zi[q * 2] = z.y; zr[q * 2 + 1] = z.z; zi[q * 2 + 1] = z.w;
  }
  float gamma = ws[FILM_OFF + ((size_t)b * HH + h) * 2];
  float beta  = ws[FILM_OFF + ((size_t)b * HH + h) * 2 + 1];
  float dcoef = Dv[h];
  const size_t off = ((size_t)b * LL + (size_t)c * LC) * HH + h;
  const float* xp = x + off;
  float* op = out + off;
  for (int i = 0; i < LC; i += 8) {
    float u[8];
    #pragma unroll
    for (int j = 0; j < 8; j++) u[j] = xp[(size_t)(i + j) * HH];
    #pragma unroll
    for (int j = 0; j < 8; j++) {
      float acc = 0.f;
      #pragma unroll
      for (int n = 0; n < NN2; n++) {
        float t0  = fmaf(-wi[n], zi[n], u[j]);
        float nzr = fmaf(wr[n], zr[n], t0);
        float nzi = fmaf(wr[n], zi[n], wi[n] * zr[n]);
        zr[n] = nzr; zi[n] = nzi;
        acc = fmaf(ctr[n], nzr, acc);
        acc = fmaf(-cti[n], nzi, acc);
      }
      float y = fmaf(dcoef, u[j], acc);
      y = fmaf(gamma, y, beta);
      // tanh-approx gelu (JAX default approximate=True)
      float y3   = y * y * y;
      float targ = 0.7978845608f * fmaf(0.044715f, y3, y);
      float e    = __expf(2.f * targ);
      float th   = 1.f - __fdividef(2.f, e + 1.f);
      op[(size_t)(i + j) * HH] = 0.5f * y * (1.f + th);
    }
  }
}

extern "C" void kernel_launch(void* const* d_in, const int* in_sizes, int n_in,
                              void* d_out, int out_size, void* d_ws, size_t ws_size,
                              hipStream_t stream) {
  const float* x          = (const float*)d_in[0];
  const float* cond       = (const float*)d_in[1];
  const float* log_dt     = (const float*)d_in[2];
  const float* C_re       = (const float*)d_in[3];
  const float* C_im       = (const float*)d_in[4];
  const float* log_A_real = (const float*)d_in[5];
  const float* A_imag     = (const float*)d_in[6];
  const float* Dv         = (const float*)d_in[7];
  const float* film_W     = (const float*)d_in[8];
  const float* film_b     = (const float*)d_in[9];
  float* out = (float*)d_out;
  float* ws  = (float*)d_ws;

  setup_kernel<<<5, 256, 0, stream>>>(log_dt, C_re, C_im, log_A_real, A_imag,
                                      cond, film_W, film_b, ws);
  pass_a<<<(BB * HH * NCHUNK) / 256, 256, 0, stream>>>(x, ws);
  pass_b<<<(BB * HH * NN2) / 256, 256, 0, stream>>>(ws);
  pass_c<<<(BB * HH * NCHUNK) / 256, 256, 0, stream>>>(x, Dv, out, ws);
}

// Round 2
// 313.830 us; speedup vs baseline: 1.0052x; 1.0052x over previous
//
#include <hip/hip_runtime.h>

typedef float v2f __attribute__((ext_vector_type(2)));

#define BB 32
#define LL 32768
#define HH 32
#define NN2 8
#define NCOND 4
#define NCHUNK 256
#define LC (LL / NCHUNK)   // 128

// ws layout (floats):
//  PARAM_OFF: per h: [wr x8][wi x8][ctr x8][cti x8]   H*32  = 1024
//  WLC_OFF  : per (h,n): (wLc_r, wLc_i)               H*N2*2 = 512   (at 1024)
//  FILM_OFF : per (b,h): (gamma, beta)                B*H*2  = 2048  (at 1536)
//  S_OFF    : per flat=(b,c,h): [zr x8][zi x8]        B*H*NCHUNK*16  (at 4096)
//             pass_a writes chunk end-states; pass_b rewrites IN PLACE with
//             the exclusive prefix (chunk initial states); pass_c reads them.
#define PARAM_OFF 0
#define WLC_OFF   1024
#define FILM_OFF  1536
#define S_OFF     4096
#define SZ_S      (BB * HH * NCHUNK * 16)   // 4,194,304 floats -> ~16.8 MB total

static __device__ __forceinline__ v2f vfma(v2f a, v2f b, v2f c) {
  return __builtin_elementwise_fma(a, b, c);
}

__global__ void setup_kernel(const float* __restrict__ log_dt,
                             const float* __restrict__ C_re,
                             const float* __restrict__ C_im,
                             const float* __restrict__ log_A_real,
                             const float* __restrict__ A_imag,
                             const float* __restrict__ cond,
                             const float* __restrict__ film_W,
                             const float* __restrict__ film_b,
                             float* __restrict__ ws) {
  int idx = blockIdx.x * blockDim.x + threadIdx.x;
  if (idx < HH * NN2) {
    int h = idx >> 3, n = idx & (NN2 - 1);
    float dt = expf(log_dt[h]);
    float ar = -expf(log_A_real[idx]);
    float ai = A_imag[idx];
    float dr = ar * dt, di = ai * dt;        // dtA
    float er = expf(dr);
    float wr = er * cosf(di);
    float wi = er * sinf(di);
    // (exp(dtA)-1)/A
    float den = ar * ar + ai * ai;
    float tr = ((wr - 1.f) * ar + wi * ai) / den;
    float ti = (wi * ar - (wr - 1.f) * ai) / den;
    float cr = C_re[idx], ci = C_im[idx];
    float ctr = 2.f * (cr * tr - ci * ti);
    float cti = 2.f * (cr * ti + ci * tr);
    float* p = ws + PARAM_OFF + h * 32;
    p[n] = wr; p[n + 8] = wi; p[n + 16] = ctr; p[n + 24] = cti;
    // w^LC
    float eL  = expf(dr * (float)LC);
    float wlr = eL * cosf(di * (float)LC);
    float wli = eL * sinf(di * (float)LC);
    float* q = ws + WLC_OFF + idx * 2;
    q[0] = wlr; q[1] = wli;
  }
  int f = idx - HH * NN2;
  if (f >= 0 && f < BB * HH) {
    int b = f >> 5, h = f & (HH - 1);
    float g  = film_b[h];
    float be = film_b[h + HH];
    #pragma unroll
    for (int c2 = 0; c2 < NCOND; c2++) {
      float cv = cond[b * NCOND + c2];
      g  = fmaf(cv, film_W[c2 * 2 * HH + h], g);
      be = fmaf(cv, film_W[c2 * 2 * HH + HH + h], be);
    }
    float* p = ws + FILM_OFF + f * 2;
    p[0] = g; p[1] = be;
  }
}

__global__ __launch_bounds__(256) void pass_a(const float* __restrict__ x,
                                              float* __restrict__ ws) {
  const int flat = blockIdx.x * 256 + threadIdx.x;
  const int h = flat & (HH - 1);
  const int c = (flat >> 5) & (NCHUNK - 1);
  const int b = flat >> 13;
  const v2f* pp = (const v2f*)(ws + PARAM_OFF + h * 32);
  v2f wr[4], wi[4], zr[4], zi[4];
  #pragma unroll
  for (int g = 0; g < 4; g++) {
    wr[g] = pp[g]; wi[g] = pp[4 + g];
    zr[g] = (v2f){0.f, 0.f}; zi[g] = (v2f){0.f, 0.f};
  }
  const float* xp = x + ((size_t)b * LL + (size_t)c * LC) * HH + h;
  for (int i = 0; i < LC; i += 8) {
    float u[8];
    #pragma unroll
    for (int j = 0; j < 8; j++) u[j] = xp[(size_t)(i + j) * HH];
    #pragma unroll
    for (int j = 0; j < 8; j++) {
      v2f us = (v2f){u[j], u[j]};
      #pragma unroll
      for (int g = 0; g < 4; g++) {
        v2f t0  = vfma(-wi[g], zi[g], us);
        v2f nzr = vfma(wr[g], zr[g], t0);
        v2f nzi = vfma(wr[g], zi[g], wi[g] * zr[g]);
        zr[g] = nzr; zi[g] = nzi;
      }
    }
  }
  v2f* Sp = (v2f*)(ws + S_OFF + (size_t)flat * 16);
  #pragma unroll
  for (int g = 0; g < 4; g++) { Sp[g] = zr[g]; Sp[4 + g] = zi[g]; }
}

__global__ void pass_b(float* __restrict__ ws) {
  int idx = blockIdx.x * blockDim.x + threadIdx.x;  // B*H*N2 = 8192
  int n = idx & (NN2 - 1);
  int h = (idx >> 3) & (HH - 1);
  int b = idx >> 8;
  float wlr = ws[WLC_OFF + (h * NN2 + n) * 2];
  float wli = ws[WLC_OFF + (h * NN2 + n) * 2 + 1];
  float Zr = 0.f, Zi = 0.f;
  const size_t stride = (size_t)HH * 16;   // per-chunk stride in floats
  size_t base = ((size_t)b * NCHUNK * HH + h) * 16 + n;
  for (int c = 0; c < NCHUNK; c++) {
    float* pr = ws + S_OFF + base + (size_t)c * stride;
    float sr = pr[0];
    float si = pr[8];
    pr[0] = Zr;          // overwrite with exclusive prefix, in place
    pr[8] = Zi;
    float nZr = fmaf(wlr, Zr, fmaf(-wli, Zi, sr));
    float nZi = fmaf(wlr, Zi, fmaf(wli, Zr, si));
    Zr = nZr; Zi = nZi;
  }
}

__global__ __launch_bounds__(256) void pass_c(const float* __restrict__ x,
                                              const float* __restrict__ Dv,
                                              float* __restrict__ out,
                                              float* __restrict__ ws) {
  const int flat = blockIdx.x * 256 + threadIdx.x;
  const int h = flat & (HH - 1);
  const int c = (flat >> 5) & (NCHUNK - 1);
  const int b = flat >> 13;
  const v2f* pp = (const v2f*)(ws + PARAM_OFF + h * 32);
  v2f wr[4], wi[4], ctr[4], cti[4], zr[4], zi[4];
  #pragma unroll
  for (int g = 0; g < 4; g++) {
    wr[g] = pp[g]; wi[g] = pp[4 + g]; ctr[g] = pp[8 + g]; cti[g] = pp[12 + g];
  }
  const v2f* Zp = (const v2f*)(ws + S_OFF + (size_t)flat * 16);
  #pragma unroll
  for (int g = 0; g < 4; g++) { zr[g] = Zp[g]; zi[g] = Zp[4 + g]; }
  float gamma = ws[FILM_OFF + ((size_t)b * HH + h) * 2];
  float beta  = ws[FILM_OFF + ((size_t)b * HH + h) * 2 + 1];
  float dcoef = Dv[h];
  const size_t off = ((size_t)b * LL + (size_t)c * LC) * HH + h;
  const float* xp = x + off;
  float* op = out + off;
  for (int i = 0; i < LC; i += 8) {
    float u[8];
    #pragma unroll
    for (int j = 0; j < 8; j++) u[j] = xp[(size_t)(i + j) * HH];
    #pragma unroll
    for (int j = 0; j < 8; j++) {
      v2f us = (v2f){u[j], u[j]};
      v2f acc = (v2f){0.f, 0.f};
      #pragma unroll
      for (int g = 0; g < 4; g++) {
        v2f t0  = vfma(-wi[g], zi[g], us);
        v2f nzr = vfma(wr[g], zr[g], t0);
        v2f nzi = vfma(wr[g], zi[g], wi[g] * zr[g]);
        zr[g] = nzr; zi[g] = nzi;
        acc = vfma(ctr[g], nzr, acc);
        acc = vfma(-cti[g], nzi, acc);
      }
      float y = acc.x + acc.y;
      y = fmaf(dcoef, u[j], y);
      y = fmaf(gamma, y, beta);
      // tanh-approx gelu (JAX default approximate=True)
      float y3   = y * y * y;
      float targ = 0.7978845608f * fmaf(0.044715f, y3, y);
      float e    = __expf(2.f * targ);
      float th   = 1.f - __fdividef(2.f, e + 1.f);
      op[(size_t)(i + j) * HH] = 0.5f * y * (1.f + th);
    }
  }
}

extern "C" void kernel_launch(void* const* d_in, const int* in_sizes, int n_in,
                              void* d_out, int out_size, void* d_ws, size_t ws_size,
                              hipStream_t stream) {
  const float* x          = (const float*)d_in[0];
  const float* cond       = (const float*)d_in[1];
  const float* log_dt     = (const float*)d_in[2];
  const float* C_re       = (const float*)d_in[3];
  const float* C_im       = (const float*)d_in[4];
  const float* log_A_real = (const float*)d_in[5];
  const float* A_imag     = (const float*)d_in[6];
  const float* Dv         = (const float*)d_in[7];
  const float* film_W     = (const float*)d_in[8];
  const float* film_b     = (const float*)d_in[9];
  float* out = (float*)d_out;
  float* ws  = (float*)d_ws;

  setup_kernel<<<5, 256, 0, stream>>>(log_dt, C_re, C_im, log_A_real, A_imag,
                                      cond, film_W, film_b, ws);
  pass_a<<<(BB * HH * NCHUNK) / 256, 256, 0, stream>>>(x, ws);
  pass_b<<<(BB * HH * NN2) / 256, 256, 0, stream>>>(ws);
  pass_c<<<(BB * HH * NCHUNK) / 256, 256, 0, stream>>>(x, Dv, out, ws);
}